// Round 20
// baseline (452.906 us; speedup 1.0000x reference)
//
#include <hip/hip_runtime.h>

#define S_ 2048
#define B_ 2
#define E_ 1024
#define H_ 16

typedef _Float16 f16x8 __attribute__((ext_vector_type(8)));
typedef _Float16 f16x4 __attribute__((ext_vector_type(4)));
typedef _Float16 f16x2 __attribute__((ext_vector_type(2)));
typedef float f32x4 __attribute__((ext_vector_type(4)));
typedef unsigned short us4_t __attribute__((ext_vector_type(4)));
typedef unsigned u32x4 __attribute__((ext_vector_type(4)));
typedef unsigned u32x2 __attribute__((ext_vector_type(2)));

static __device__ __forceinline__ unsigned short f2h(float x) {
  _Float16 h = (_Float16)x;   // RNE
  return __builtin_bit_cast(unsigned short, h);
}
static __device__ __forceinline__ unsigned pk_f16(float a, float b) {
  auto r = __builtin_amdgcn_cvt_pkrtz(a, b);   // lo=a, hi=b (RTZ - p only)
  return __builtin_bit_cast(unsigned, r);
}

// ---------------- all f32 -> fp16 conversions in ONE launch (RNE) ----------------
// vec4 segments: q 1M | k 1M | v 1M | ipw 768K | outw 256K | posb 2M = 6M total
__global__ void k_cvt_all(const float* __restrict__ q, const float* __restrict__ k,
                          const float* __restrict__ v, const float* __restrict__ ipw,
                          const float* __restrict__ outw, const float* __restrict__ posb,
                          unsigned short* __restrict__ qx, unsigned short* __restrict__ kx,
                          unsigned short* __restrict__ vx, unsigned short* __restrict__ w3,
                          unsigned short* __restrict__ ow, unsigned short* __restrict__ pb16) {
  const int M1 = 1 << 20;
  int i = blockIdx.x * blockDim.x + threadIdx.x;
  int stp = gridDim.x * blockDim.x;
  for (; i < 6 * M1; i += stp) {
    const float* src;
    unsigned short* dst;
    int j;
    if (i < M1)                   { src = q;    dst = qx;   j = i; }
    else if (i < 2 * M1)          { src = k;    dst = kx;   j = i - M1; }
    else if (i < 3 * M1)          { src = v;    dst = vx;   j = i - 2 * M1; }
    else if (i < 3 * M1 + 786432) { src = ipw;  dst = w3;   j = i - 3 * M1; }
    else if (i < 4 * M1)          { src = outw; dst = ow;   j = i - 3 * M1 - 786432; }
    else                          { src = posb; dst = pb16; j = i - 4 * M1; }
    f32x4 x = ((const f32x4*)src)[j];
    us4_t h;
    #pragma unroll
    for (int e = 0; e < 4; ++e) h[e] = f2h(x[e]);
    ((us4_t*)dst)[j] = h;
  }
}

// ---------------- q/k projection: plain fp16 GEMM ----------------
__launch_bounds__(256, 2)
__global__ void k_proj_qk(const unsigned short* __restrict__ qx, const unsigned short* __restrict__ kx,
                          const unsigned short* __restrict__ wqk, const float* __restrict__ bias,
                          unsigned short* __restrict__ qf, unsigned short* __restrict__ kf) {
  const int z = blockIdx.z;
  const unsigned short* A = z ? kx : qx;
  const unsigned short* W = wqk + (size_t)z * (1024 * 1024);
  unsigned short* C = z ? kf : qf;
  const float* bia = bias + z * 1024;
  const float scale = z ? 1.0f : 0.125f;

  __shared__ unsigned short sA[128][40], sB[128][40];

  const int t = threadIdx.x;
  const int wid = t >> 6, l = t & 63, g = l >> 4, c = l & 15;
  const int wr = wid >> 1, wc = wid & 1;
  const int mb = blockIdx.x * 128, nb = blockIdx.y * 128;
  const int sr = t >> 1, sc = (t & 1) * 16;

  f32x4 acc[4][4] = {};

  for (int k0 = 0; k0 < 1024; k0 += 32) {
    __syncthreads();
    {
      const unsigned short* pa = A + (size_t)(mb + sr) * 1024 + k0 + sc;
      const unsigned short* pb = W + (size_t)(nb + sr) * 1024 + k0 + sc;
      *(f16x8*)&sA[sr][sc]     = *(const f16x8*)pa;
      *(f16x8*)&sA[sr][sc + 8] = *(const f16x8*)(pa + 8);
      *(f16x8*)&sB[sr][sc]     = *(const f16x8*)pb;
      *(f16x8*)&sB[sr][sc + 8] = *(const f16x8*)(pb + 8);
    }
    __syncthreads();
    f16x8 af[4], bf[4];
    #pragma unroll
    for (int i = 0; i < 4; ++i) {
      af[i] = *(const f16x8*)&sA[wr * 64 + i * 16 + c][g * 8];
      bf[i] = *(const f16x8*)&sB[wc * 64 + i * 16 + c][g * 8];
    }
    #pragma unroll
    for (int i = 0; i < 4; ++i)
      #pragma unroll
      for (int j = 0; j < 4; ++j)
        acc[i][j] = __builtin_amdgcn_mfma_f32_16x16x32_f16(af[i], bf[j], acc[i][j], 0, 0, 0);
  }
  #pragma unroll
  for (int i = 0; i < 4; ++i)
    #pragma unroll
    for (int j = 0; j < 4; ++j)
      #pragma unroll
      for (int rr = 0; rr < 4; ++rr) {
        int m = mb + wr * 64 + i * 16 + 4 * g + rr;
        int n = nb + wc * 64 + j * 16 + c;
        float v = (acc[i][j][rr] + bia[n]) * scale;
        C[(size_t)m * 1024 + n] = f2h(v);
      }
}

// ---------------- v projection (fp16), writes V^T: VT[b][e'][j] ----------------
__launch_bounds__(256, 2)
__global__ void k_proj_v(const unsigned short* __restrict__ wv, const unsigned short* __restrict__ vx,
                         const float* __restrict__ bias, unsigned short* __restrict__ VT) {
  __shared__ unsigned short sA[128][40], sB[128][40];
  const int t = threadIdx.x;
  const int wid = t >> 6, l = t & 63, g = l >> 4, c = l & 15;
  const int wr = wid >> 1, wc = wid & 1;
  const int mb = blockIdx.x * 128;   // e' base
  const int nb = blockIdx.y * 128;   // n = b*2048 + j
  const int bb = nb >> 11;
  const int jb = nb & 2047;
  const int sr = t >> 1, sc = (t & 1) * 16;

  f32x4 acc[4][4] = {};
  for (int k0 = 0; k0 < 1024; k0 += 32) {
    __syncthreads();
    {
      const unsigned short* pa = wv + (size_t)(mb + sr) * 1024 + k0 + sc;
      const unsigned short* pb = vx + ((size_t)(jb + sr) * 2 + bb) * 1024 + k0 + sc;
      *(f16x8*)&sA[sr][sc]     = *(const f16x8*)pa;
      *(f16x8*)&sA[sr][sc + 8] = *(const f16x8*)(pa + 8);
      *(f16x8*)&sB[sr][sc]     = *(const f16x8*)pb;
      *(f16x8*)&sB[sr][sc + 8] = *(const f16x8*)(pb + 8);
    }
    __syncthreads();
    f16x8 af[4], bf[4];
    #pragma unroll
    for (int i = 0; i < 4; ++i) {
      af[i] = *(const f16x8*)&sA[wr * 64 + i * 16 + c][g * 8];
      bf[i] = *(const f16x8*)&sB[wc * 64 + i * 16 + c][g * 8];
    }
    #pragma unroll
    for (int i = 0; i < 4; ++i)
      #pragma unroll
      for (int j = 0; j < 4; ++j)
        acc[i][j] = __builtin_amdgcn_mfma_f32_16x16x32_f16(af[i], bf[j], acc[i][j], 0, 0, 0);
  }
  #pragma unroll
  for (int i = 0; i < 4; ++i)
    #pragma unroll
    for (int j = 0; j < 4; ++j)
      #pragma unroll
      for (int rr = 0; rr < 4; ++rr) {
        int m = mb + wr * 64 + i * 16 + 4 * g + rr;
        int jj = jb + wc * 64 + j * 16 + c;
        float v = acc[i][j][rr] + bias[2048 + m];
        VT[(size_t)bb * (1024 * 2048) + (size_t)m * 2048 + jj] = f2h(v);
      }
}

// ---------------- fused attention v10: QBLK=32 (2 q-tiles share staged K/V) ----------------
// Block=(b,h,qt2): 512 thr = 8 waves. Wave wid: qtile=wid>>2 (0/1), ctile=wid&3.
// Waves 0-3 compute q-rows qt2*32..+16, waves 4-7 the next 16; all share S_k/S_v.
// QK: 2x mfma_f32_16x16x32_f16; acc@(g,c)=s[k=4g+rr][q=c] == B-frag of K=16
// MFMA -> PV B direct from packed fp16 p regs. p = exp(s-8) (cancels in norm).
// Staging: global_load_lds w=16 (1 K-call + 1 V-call per wave per stage covers
// the full 8KB+8KB tile across 8 waves), linear LDS dest, XOR swizzle folded
// into per-lane GLOBAL source slot (rule #21). fp16 posb.
__launch_bounds__(512, 2)
__global__ void k_attn_pv(const unsigned short* __restrict__ qf, const unsigned short* __restrict__ kf,
                          const unsigned short* __restrict__ VT, const unsigned short* __restrict__ pb16,
                          float* __restrict__ attn, unsigned short* __restrict__ oc) {
  // h-major XCD chunking: 2048 blocks, 256/XCD -> 2 heads per XCD
  const int swz = (int)((blockIdx.x & 7) * 256 + (blockIdx.x >> 3));
  const int h = swz >> 7;
  const int b = (swz >> 6) & 1;
  const int qt2 = swz & 63;

  const int t = threadIdx.x;
  const int wid = t >> 6, l = t & 63, g = l >> 4, c = l & 15;
  const int qtile = wid >> 2, ctile = wid & 3;

  __shared__ unsigned smem[8704];        // staging: S_k[2][2048] S_v[2][2048] (32KB); epilogue: ored 34.8KB
  __shared__ float lds_red[8][16];
  unsigned* S_k = smem;
  unsigned* S_v = smem + 4096;

  const int qrow = qt2 * 32 + qtile * 16 + c;
  const size_t qoff = ((size_t)qrow * 2 + b) * 1024 + h * 64 + g * 8;
  const f16x8 qfr0 = *(const f16x8*)(qf + qoff);
  const f16x8 qfr1 = *(const f16x8*)(qf + qoff + 32);

  const unsigned short* kfb = kf + (size_t)b * 1024 + h * 64;
  const unsigned short* vtb = VT + ((size_t)b * 1024 + h * 64) * 2048;
  const unsigned short* pbRow = pb16 + (size_t)b * S_ * S_ + (size_t)qrow * S_ + ctile * 16;

  const int rb = t >> 3;                 // 0..63 (full tile across 512 threads)
  const int lsl = (t & 7) ^ (rb & 7);    // pre-swizzled global slot

  #define LDSRD(base, row, slot) \
    __builtin_bit_cast(f16x8, *(const u32x4*)&(base)[(row) * 32 + ((((slot) ^ ((row) & 7))) * 4)])

  // one K-call + one V-call per wave per stage; 8 waves cover 8KB K + 8KB V.
  // LDS dest per wave: buf*8KB + wid*1KB + lane*16B (linear; == rb*128+slot*16)
  #define GLDS(stg, buf) do { \
    __builtin_amdgcn_global_load_lds( \
        (const __attribute__((address_space(1))) unsigned*)(kfb + (size_t)((stg) * 64 + rb) * 2048 + lsl * 8), \
        (__attribute__((address_space(3))) unsigned*)&S_k[(buf) * 2048 + wid * 256], 16, 0, 0); \
    __builtin_amdgcn_global_load_lds( \
        (const __attribute__((address_space(1))) unsigned*)(vtb + (size_t)rb * 2048 + (stg) * 64 + lsl * 8), \
        (__attribute__((address_space(3))) unsigned*)&S_v[(buf) * 2048 + wid * 256], 16, 0, 0); \
  } while (0)

  f32x4 bias[2];
  unsigned psc0[32], psc1[32];
  float lsum = 0.f;
  f32x4 oacc[4] = {};

  // prologue
  GLDS(0, 0);
  {
    f16x4 b0 = *(const f16x4*)(pbRow + 4 * g);
    bias[0][0] = (float)b0[0] - 8.f; bias[0][1] = (float)b0[1] - 8.f;
    bias[0][2] = (float)b0[2] - 8.f; bias[0][3] = (float)b0[3] - 8.f;
  }
  __syncthreads();

  #pragma unroll
  for (int st = 0; st < 32; ++st) {
    const int cur = st & 1;
    if (st < 31) GLDS(st + 1, cur ^ 1);
    if (st < 31) {
      f16x4 bb = *(const f16x4*)(pbRow + (st + 1) * 64 + 4 * g);
      bias[cur ^ 1][0] = (float)bb[0] - 8.f; bias[cur ^ 1][1] = (float)bb[1] - 8.f;
      bias[cur ^ 1][2] = (float)bb[2] - 8.f; bias[cur ^ 1][3] = (float)bb[3] - 8.f;
    }

    // ---- QK(st): 2 MFMAs ----
    {
      const int row = ctile * 16 + c;
      const unsigned* kb = S_k + cur * 2048;
      f16x8 kfr0 = LDSRD(kb, row, g);
      f16x8 kfr1 = LDSRD(kb, row, 4 + g);
      f32x4 aA = {}, aB = {};
      aA = __builtin_amdgcn_mfma_f32_16x16x32_f16(kfr0, qfr0, aA, 0, 0, 0);
      aB = __builtin_amdgcn_mfma_f32_16x16x32_f16(kfr1, qfr1, aB, 0, 0, 0);
      float p0 = __expf(aA[0] + aB[0] + bias[cur][0]);
      float p1 = __expf(aA[1] + aB[1] + bias[cur][1]);
      float p2 = __expf(aA[2] + aB[2] + bias[cur][2]);
      float p3 = __expf(aA[3] + aB[3] + bias[cur][3]);
      lsum += (p0 + p1) + (p2 + p3);
      psc0[st] = pk_f16(p0, p1);
      psc1[st] = pk_f16(p2, p3);
    }

    // ---- PV(st): B from psc regs; A = V^T from LDS ----
    {
      u32x2 br; br[0] = psc0[st]; br[1] = psc1[st];
      const f16x4 bfrag = __builtin_bit_cast(f16x4, br);
      const unsigned* vb = S_v + cur * 2048;
      #pragma unroll
      for (int dt = 0; dt < 4; ++dt) {
        const int row = dt * 16 + c;
        const int sl = (2 * ctile + (g >> 1)) ^ (row & 7);
        u32x2 ar = *(const u32x2*)&vb[row * 32 + sl * 4 + 2 * (g & 1)];
        oacc[dt] = __builtin_amdgcn_mfma_f32_16x16x16f16(__builtin_bit_cast(f16x4, ar), bfrag, oacc[dt], 0, 0, 0);
      }
    }

    __syncthreads();   // drains vmcnt (st+1 loads) + orders buf reuse
  }

  // ---- softmax denominator (within each 4-wave q-tile group) ----
  lsum += __shfl_xor(lsum, 16, 64);
  lsum += __shfl_xor(lsum, 32, 64);
  if (l < 16) lds_red[wid][l] = lsum;
  __syncthreads();
  const int gb = qtile * 4;
  const float inv = 1.0f / ((lds_red[gb + 0][c] + lds_red[gb + 1][c]) +
                            (lds_red[gb + 2][c] + lds_red[gb + 3][c]));

  // ---- cross-wave out reduce (ored aliases staging LDS, stride 68) ----
  float* ored = (float*)smem;            // [8 waves][16 q][68]
  __syncthreads();                       // all LDS staging reads done
  #pragma unroll
  for (int dt = 0; dt < 4; ++dt) {
    f32x4 o = oacc[dt];
    o[0] *= inv; o[1] *= inv; o[2] *= inv; o[3] *= inv;
    *(f32x4*)&ored[(wid * 16 + c) * 68 + dt * 16 + 4 * g] = o;
  }
  __syncthreads();
  {
    const int q_i = t >> 8;              // q-tile 0/1
    const int rem = t & 255;
    const int q = rem >> 4;
    const int d0 = (rem & 15) * 4;
    const int wb = q_i * 4;
    f32x4 s0 = *(const f32x4*)&ored[((wb + 0) * 16 + q) * 68 + d0];
    f32x4 s1 = *(const f32x4*)&ored[((wb + 1) * 16 + q) * 68 + d0];
    f32x4 s2 = *(const f32x4*)&ored[((wb + 2) * 16 + q) * 68 + d0];
    f32x4 s3 = *(const f32x4*)&ored[((wb + 3) * 16 + q) * 68 + d0];
    f32x4 s;
    s[0] = (s0[0] + s1[0]) + (s2[0] + s3[0]);
    s[1] = (s0[1] + s1[1]) + (s2[1] + s3[1]);
    s[2] = (s0[2] + s1[2]) + (s2[2] + s3[2]);
    s[3] = (s0[3] + s1[3]) + (s2[3] + s3[3]);
    u32x2 pk;
    pk[0] = pk_f16(s[0], s[1]);
    pk[1] = pk_f16(s[2], s[3]);
    *(u32x2*)&oc[((size_t)(qt2 * 32 + q_i * 16 + q) * 2 + b) * 1024 + h * 64 + d0] = pk;
  }

  // ---- attn write (normalized), unpack fp16 p ----
  float* arow = attn + ((size_t)(b * 16 + h) * S_ + qrow) * S_ + ctile * 16;
  #pragma unroll
  for (int st = 0; st < 32; ++st) {
    f16x2 h0 = __builtin_bit_cast(f16x2, psc0[st]);
    f16x2 h1 = __builtin_bit_cast(f16x2, psc1[st]);
    f32x4 o;
    o[0] = (float)h0[0] * inv;
    o[1] = (float)h0[1] * inv;
    o[2] = (float)h1[0] * inv;
    o[3] = (float)h1[1] * inv;
    *(f32x4*)(arow + (size_t)st * 64 + 4 * g) = o;
  }
  #undef LDSRD
  #undef GLDS
}

// ---------------- out projection (fp16) ----------------
__launch_bounds__(256, 2)
__global__ void k_outproj(const unsigned short* __restrict__ oc, const unsigned short* __restrict__ ow,
                          const float* __restrict__ ob, float* __restrict__ out) {
  __shared__ unsigned short sA[128][40], sB[128][40];
  const int t = threadIdx.x;
  const int wid = t >> 6, l = t & 63, g = l >> 4, c = l & 15;
  const int wr = wid >> 1, wc = wid & 1;
  const int mb = blockIdx.x * 128, nb = blockIdx.y * 128;
  const int sr = t >> 1, sc = (t & 1) * 16;

  f32x4 acc[4][4] = {};
  for (int k0 = 0; k0 < 1024; k0 += 32) {
    __syncthreads();
    {
      const unsigned short* pa = oc + (size_t)(mb + sr) * 1024 + k0 + sc;
      const unsigned short* pb = ow + (size_t)(nb + sr) * 1024 + k0 + sc;
      *(f16x8*)&sA[sr][sc]     = *(const f16x8*)pa;
      *(f16x8*)&sA[sr][sc + 8] = *(const f16x8*)(pa + 8);
      *(f16x8*)&sB[sr][sc]     = *(const f16x8*)pb;
      *(f16x8*)&sB[sr][sc + 8] = *(const f16x8*)(pb + 8);
    }
    __syncthreads();
    f16x8 af[4], bf[4];
    #pragma unroll
    for (int i = 0; i < 4; ++i) {
      af[i] = *(const f16x8*)&sA[wr * 64 + i * 16 + c][g * 8];
      bf[i] = *(const f16x8*)&sB[wc * 64 + i * 16 + c][g * 8];
    }
    #pragma unroll
    for (int i = 0; i < 4; ++i)
      #pragma unroll
      for (int j = 0; j < 4; ++j)
        acc[i][j] = __builtin_amdgcn_mfma_f32_16x16x32_f16(af[i], bf[j], acc[i][j], 0, 0, 0);
  }
  #pragma unroll
  for (int i = 0; i < 4; ++i)
    #pragma unroll
    for (int j = 0; j < 4; ++j)
      #pragma unroll
      for (int rr = 0; rr < 4; ++rr) {
        int m = mb + wr * 64 + i * 16 + 4 * g + rr;
        int n = nb + wc * 64 + j * 16 + c;
        out[(size_t)m * 1024 + n] = acc[i][j][rr] + ob[n];
      }
}

extern "C" void kernel_launch(void* const* d_in, const int* in_sizes, int n_in,
                              void* d_out, int out_size, void* d_ws, size_t ws_size,
                              hipStream_t stream) {
  (void)in_sizes; (void)n_in; (void)out_size; (void)ws_size;
  const float* query = (const float*)d_in[0];
  const float* keyi  = (const float*)d_in[1];
  const float* value = (const float*)d_in[2];
  const float* posb  = (const float*)d_in[3];
  const float* ipw   = (const float*)d_in[4];
  const float* ipb   = (const float*)d_in[5];
  const float* outw  = (const float*)d_in[6];
  const float* outb  = (const float*)d_in[7];
  float* out = (float*)d_out;
  float* attn = out + (size_t)S_ * B_ * E_;

  char* ws = (char*)d_ws;
  size_t off = 0;
  auto alloc = [&](size_t bytes) -> void* {
    void* p = ws + off;
    off += (bytes + 255) & ~(size_t)255;
    return p;
  };
  const size_t NTOK = (size_t)S_ * B_;  // 4096
  unsigned short* qx   = (unsigned short*)alloc(NTOK * 1024 * 2);
  unsigned short* kx   = (unsigned short*)alloc(NTOK * 1024 * 2);
  unsigned short* vx   = (unsigned short*)alloc(NTOK * 1024 * 2);
  unsigned short* w3   = (unsigned short*)alloc((size_t)3072 * 1024 * 2);
  unsigned short* ow   = (unsigned short*)alloc((size_t)1024 * 1024 * 2);
  unsigned short* pb16 = (unsigned short*)alloc((size_t)B_ * S_ * S_ * 2);
  unsigned short* qf   = (unsigned short*)alloc(NTOK * 1024 * 2);
  unsigned short* kf   = (unsigned short*)alloc(NTOK * 1024 * 2);
  unsigned short* VT   = (unsigned short*)alloc((size_t)2 * 1024 * 2048 * 2);
  unsigned short* oc   = (unsigned short*)alloc(NTOK * 1024 * 2);

  k_cvt_all<<<3072, 256, 0, stream>>>(query, keyi, value, ipw, outw, posb,
                                      qx, kx, vx, w3, ow, pb16);

  k_proj_qk<<<dim3(32, 8, 2), 256, 0, stream>>>(qx, kx, w3, ipb, qf, kf);
  k_proj_v<<<dim3(8, 32), 256, 0, stream>>>(w3 + (size_t)2048 * 1024, vx, ipb, VT);
  k_attn_pv<<<2048, 512, 0, stream>>>(qf, kf, VT, pb16, attn, oc);
  k_outproj<<<dim3(32, 8), 256, 0, stream>>>(oc, ow, outb, out);
}

// Round 21
// 355.553 us; speedup vs baseline: 1.2738x; 1.2738x over previous
//
#include <hip/hip_runtime.h>

#define S_ 2048
#define B_ 2
#define E_ 1024
#define H_ 16

typedef _Float16 f16x8 __attribute__((ext_vector_type(8)));
typedef _Float16 f16x4 __attribute__((ext_vector_type(4)));
typedef _Float16 f16x2 __attribute__((ext_vector_type(2)));
typedef float f32x4 __attribute__((ext_vector_type(4)));
typedef unsigned short us4_t __attribute__((ext_vector_type(4)));
typedef unsigned u32x4 __attribute__((ext_vector_type(4)));
typedef unsigned u32x2 __attribute__((ext_vector_type(2)));

static __device__ __forceinline__ unsigned short f2h(float x) {
  _Float16 h = (_Float16)x;   // RNE
  return __builtin_bit_cast(unsigned short, h);
}
static __device__ __forceinline__ unsigned pk_f16(float a, float b) {
  auto r = __builtin_amdgcn_cvt_pkrtz(a, b);   // lo=a, hi=b (RTZ - p only)
  return __builtin_bit_cast(unsigned, r);
}

// ---------------- all f32 -> fp16 conversions in ONE launch (RNE) ----------------
// vec4 segments: q 1M | k 1M | v 1M | ipw 768K | outw 256K | posb 2M = 6M total
__global__ void k_cvt_all(const float* __restrict__ q, const float* __restrict__ k,
                          const float* __restrict__ v, const float* __restrict__ ipw,
                          const float* __restrict__ outw, const float* __restrict__ posb,
                          unsigned short* __restrict__ qx, unsigned short* __restrict__ kx,
                          unsigned short* __restrict__ vx, unsigned short* __restrict__ w3,
                          unsigned short* __restrict__ ow, unsigned short* __restrict__ pb16) {
  const int M1 = 1 << 20;
  int i = blockIdx.x * blockDim.x + threadIdx.x;
  int stp = gridDim.x * blockDim.x;
  for (; i < 6 * M1; i += stp) {
    const float* src;
    unsigned short* dst;
    int j;
    if (i < M1)                   { src = q;    dst = qx;   j = i; }
    else if (i < 2 * M1)          { src = k;    dst = kx;   j = i - M1; }
    else if (i < 3 * M1)          { src = v;    dst = vx;   j = i - 2 * M1; }
    else if (i < 3 * M1 + 786432) { src = ipw;  dst = w3;   j = i - 3 * M1; }
    else if (i < 4 * M1)          { src = outw; dst = ow;   j = i - 3 * M1 - 786432; }
    else                          { src = posb; dst = pb16; j = i - 4 * M1; }
    f32x4 x = ((const f32x4*)src)[j];
    us4_t h;
    #pragma unroll
    for (int e = 0; e < 4; ++e) h[e] = f2h(x[e]);
    ((us4_t*)dst)[j] = h;
  }
}

// ---------------- q/k projection: plain fp16 GEMM ----------------
__launch_bounds__(256, 2)
__global__ void k_proj_qk(const unsigned short* __restrict__ qx, const unsigned short* __restrict__ kx,
                          const unsigned short* __restrict__ wqk, const float* __restrict__ bias,
                          unsigned short* __restrict__ qf, unsigned short* __restrict__ kf) {
  const int z = blockIdx.z;
  const unsigned short* A = z ? kx : qx;
  const unsigned short* W = wqk + (size_t)z * (1024 * 1024);
  unsigned short* C = z ? kf : qf;
  const float* bia = bias + z * 1024;
  const float scale = z ? 1.0f : 0.125f;

  __shared__ unsigned short sA[128][40], sB[128][40];

  const int t = threadIdx.x;
  const int wid = t >> 6, l = t & 63, g = l >> 4, c = l & 15;
  const int wr = wid >> 1, wc = wid & 1;
  const int mb = blockIdx.x * 128, nb = blockIdx.y * 128;
  const int sr = t >> 1, sc = (t & 1) * 16;

  f32x4 acc[4][4] = {};

  for (int k0 = 0; k0 < 1024; k0 += 32) {
    __syncthreads();
    {
      const unsigned short* pa = A + (size_t)(mb + sr) * 1024 + k0 + sc;
      const unsigned short* pb = W + (size_t)(nb + sr) * 1024 + k0 + sc;
      *(f16x8*)&sA[sr][sc]     = *(const f16x8*)pa;
      *(f16x8*)&sA[sr][sc + 8] = *(const f16x8*)(pa + 8);
      *(f16x8*)&sB[sr][sc]     = *(const f16x8*)pb;
      *(f16x8*)&sB[sr][sc + 8] = *(const f16x8*)(pb + 8);
    }
    __syncthreads();
    f16x8 af[4], bf[4];
    #pragma unroll
    for (int i = 0; i < 4; ++i) {
      af[i] = *(const f16x8*)&sA[wr * 64 + i * 16 + c][g * 8];
      bf[i] = *(const f16x8*)&sB[wc * 64 + i * 16 + c][g * 8];
    }
    #pragma unroll
    for (int i = 0; i < 4; ++i)
      #pragma unroll
      for (int j = 0; j < 4; ++j)
        acc[i][j] = __builtin_amdgcn_mfma_f32_16x16x32_f16(af[i], bf[j], acc[i][j], 0, 0, 0);
  }
  #pragma unroll
  for (int i = 0; i < 4; ++i)
    #pragma unroll
    for (int j = 0; j < 4; ++j)
      #pragma unroll
      for (int rr = 0; rr < 4; ++rr) {
        int m = mb + wr * 64 + i * 16 + 4 * g + rr;
        int n = nb + wc * 64 + j * 16 + c;
        float v = (acc[i][j][rr] + bia[n]) * scale;
        C[(size_t)m * 1024 + n] = f2h(v);
      }
}

// ---------------- v projection (fp16), writes V^T: VT[b][e'][j] ----------------
__launch_bounds__(256, 2)
__global__ void k_proj_v(const unsigned short* __restrict__ wv, const unsigned short* __restrict__ vx,
                         const float* __restrict__ bias, unsigned short* __restrict__ VT) {
  __shared__ unsigned short sA[128][40], sB[128][40];
  const int t = threadIdx.x;
  const int wid = t >> 6, l = t & 63, g = l >> 4, c = l & 15;
  const int wr = wid >> 1, wc = wid & 1;
  const int mb = blockIdx.x * 128;   // e' base
  const int nb = blockIdx.y * 128;   // n = b*2048 + j
  const int bb = nb >> 11;
  const int jb = nb & 2047;
  const int sr = t >> 1, sc = (t & 1) * 16;

  f32x4 acc[4][4] = {};
  for (int k0 = 0; k0 < 1024; k0 += 32) {
    __syncthreads();
    {
      const unsigned short* pa = wv + (size_t)(mb + sr) * 1024 + k0 + sc;
      const unsigned short* pb = vx + ((size_t)(jb + sr) * 2 + bb) * 1024 + k0 + sc;
      *(f16x8*)&sA[sr][sc]     = *(const f16x8*)pa;
      *(f16x8*)&sA[sr][sc + 8] = *(const f16x8*)(pa + 8);
      *(f16x8*)&sB[sr][sc]     = *(const f16x8*)pb;
      *(f16x8*)&sB[sr][sc + 8] = *(const f16x8*)(pb + 8);
    }
    __syncthreads();
    f16x8 af[4], bf[4];
    #pragma unroll
    for (int i = 0; i < 4; ++i) {
      af[i] = *(const f16x8*)&sA[wr * 64 + i * 16 + c][g * 8];
      bf[i] = *(const f16x8*)&sB[wc * 64 + i * 16 + c][g * 8];
    }
    #pragma unroll
    for (int i = 0; i < 4; ++i)
      #pragma unroll
      for (int j = 0; j < 4; ++j)
        acc[i][j] = __builtin_amdgcn_mfma_f32_16x16x32_f16(af[i], bf[j], acc[i][j], 0, 0, 0);
  }
  #pragma unroll
  for (int i = 0; i < 4; ++i)
    #pragma unroll
    for (int j = 0; j < 4; ++j)
      #pragma unroll
      for (int rr = 0; rr < 4; ++rr) {
        int m = mb + wr * 64 + i * 16 + 4 * g + rr;
        int jj = jb + wc * 64 + j * 16 + c;
        float v = acc[i][j][rr] + bias[2048 + m];
        VT[(size_t)bb * (1024 * 2048) + (size_t)m * 2048 + jj] = f2h(v);
      }
}

// ---------------- fused attention v8b (R19-verified best) ----------------
// Block=(b,h,qt), 256 thr = 4 waves; wave ct owns cols ct*16 of each KVBLK=64.
// QK: 2x mfma_f32_16x16x32_f16; acc@(g,c)=s[k=4g+rr][q=c] == B-frag of K=16
// MFMA -> PV B direct from packed fp16 p regs. p = exp(s-8) (cancels in norm).
// Staging: global_load_lds w=16, linear LDS dest (wave base + lane*16B), XOR
// swizzle folded into per-lane GLOBAL source slot (rule #21). Loads for st+1
// issue at stage-st top; stage-end __syncthreads drains them. fp16 posb.
__launch_bounds__(256, 4)
__global__ void k_attn_pv(const unsigned short* __restrict__ qf, const unsigned short* __restrict__ kf,
                          const unsigned short* __restrict__ VT, const unsigned short* __restrict__ pb16,
                          float* __restrict__ attn, unsigned short* __restrict__ oc) {
  // h-major XCD chunking (R6-validated)
  const int swz = (int)((blockIdx.x & 7) * 512 + (blockIdx.x >> 3));
  const int h = swz >> 8;
  const int b = (swz >> 7) & 1;
  const int qt = swz & 127;

  const int t = threadIdx.x;
  const int wid = t >> 6, l = t & 63, g = l >> 4, c = l & 15;
  const int ct = wid;

  __shared__ unsigned smem[8192];        // S_k[2][2048] S_v[2][2048]
  __shared__ float lds_red[4][16];
  unsigned* S_k = smem;
  unsigned* S_v = smem + 4096;

  const size_t qoff = ((size_t)(qt * 16 + c) * 2 + b) * 1024 + h * 64 + g * 8;
  const f16x8 qfr0 = *(const f16x8*)(qf + qoff);
  const f16x8 qfr1 = *(const f16x8*)(qf + qoff + 32);

  const unsigned short* kfb = kf + (size_t)b * 1024 + h * 64;
  const unsigned short* vtb = VT + ((size_t)b * 1024 + h * 64) * 2048;
  const unsigned short* pbRow = pb16 + (size_t)b * S_ * S_ + (size_t)(qt * 16 + c) * S_ + ct * 16;

  const int rb = t >> 3;                 // 0..31
  const int lsl = (t & 7) ^ (rb & 7);    // pre-swizzled global slot

  #define LDSRD(base, row, slot) \
    __builtin_bit_cast(f16x8, *(const u32x4*)&(base)[(row) * 32 + ((((slot) ^ ((row) & 7))) * 4)])

  #define GLDS(stg, buf) do { \
    __builtin_amdgcn_global_load_lds( \
        (const __attribute__((address_space(1))) unsigned*)(kfb + (size_t)((stg) * 64 + rb) * 2048 + lsl * 8), \
        (__attribute__((address_space(3))) unsigned*)&S_k[(buf) * 2048 + wid * 256], 16, 0, 0); \
    __builtin_amdgcn_global_load_lds( \
        (const __attribute__((address_space(1))) unsigned*)(kfb + (size_t)((stg) * 64 + rb + 32) * 2048 + lsl * 8), \
        (__attribute__((address_space(3))) unsigned*)&S_k[(buf) * 2048 + 1024 + wid * 256], 16, 0, 0); \
    __builtin_amdgcn_global_load_lds( \
        (const __attribute__((address_space(1))) unsigned*)(vtb + (size_t)rb * 2048 + (stg) * 64 + lsl * 8), \
        (__attribute__((address_space(3))) unsigned*)&S_v[(buf) * 2048 + wid * 256], 16, 0, 0); \
    __builtin_amdgcn_global_load_lds( \
        (const __attribute__((address_space(1))) unsigned*)(vtb + (size_t)(rb + 32) * 2048 + (stg) * 64 + lsl * 8), \
        (__attribute__((address_space(3))) unsigned*)&S_v[(buf) * 2048 + 1024 + wid * 256], 16, 0, 0); \
  } while (0)

  f32x4 bias[2];
  unsigned psc0[32], psc1[32];
  float lsum = 0.f;
  f32x4 oacc[4] = {};

  // prologue: stage 0 -> buf 0; bias0 (fp16 -> f32, minus 8)
  GLDS(0, 0);
  {
    f16x4 b0 = *(const f16x4*)(pbRow + 4 * g);
    bias[0][0] = (float)b0[0] - 8.f; bias[0][1] = (float)b0[1] - 8.f;
    bias[0][2] = (float)b0[2] - 8.f; bias[0][3] = (float)b0[3] - 8.f;
  }
  __syncthreads();   // drains vmcnt -> buf0 ready

  #pragma unroll
  for (int st = 0; st < 32; ++st) {
    const int cur = st & 1;
    // issue loads for st+1 into buf^1 (read last at st-1; barrier separated)
    if (st < 31) GLDS(st + 1, cur ^ 1);
    if (st < 31) {
      f16x4 bb = *(const f16x4*)(pbRow + (st + 1) * 64 + 4 * g);
      bias[cur ^ 1][0] = (float)bb[0] - 8.f; bias[cur ^ 1][1] = (float)bb[1] - 8.f;
      bias[cur ^ 1][2] = (float)bb[2] - 8.f; bias[cur ^ 1][3] = (float)bb[3] - 8.f;
    }

    // ---- QK(st): 2 MFMAs, independent chains ----
    {
      const int row = ct * 16 + c;
      const unsigned* kb = S_k + cur * 2048;
      f16x8 kfr0 = LDSRD(kb, row, g);
      f16x8 kfr1 = LDSRD(kb, row, 4 + g);
      f32x4 aA = {}, aB = {};
      aA = __builtin_amdgcn_mfma_f32_16x16x32_f16(kfr0, qfr0, aA, 0, 0, 0);
      aB = __builtin_amdgcn_mfma_f32_16x16x32_f16(kfr1, qfr1, aB, 0, 0, 0);
      float p0 = __expf(aA[0] + aB[0] + bias[cur][0]);
      float p1 = __expf(aA[1] + aB[1] + bias[cur][1]);
      float p2 = __expf(aA[2] + aB[2] + bias[cur][2]);
      float p3 = __expf(aA[3] + aB[3] + bias[cur][3]);
      lsum += (p0 + p1) + (p2 + p3);
      psc0[st] = pk_f16(p0, p1);
      psc1[st] = pk_f16(p2, p3);
    }

    // ---- PV(st): B from psc regs (fp16, K=16); A = V^T from LDS ----
    {
      u32x2 br; br[0] = psc0[st]; br[1] = psc1[st];
      const f16x4 bfrag = __builtin_bit_cast(f16x4, br);
      const unsigned* vb = S_v + cur * 2048;
      #pragma unroll
      for (int dt = 0; dt < 4; ++dt) {
        const int row = dt * 16 + c;
        const int sl = (2 * ct + (g >> 1)) ^ (row & 7);
        u32x2 ar = *(const u32x2*)&vb[row * 32 + sl * 4 + 2 * (g & 1)];
        oacc[dt] = __builtin_amdgcn_mfma_f32_16x16x16f16(__builtin_bit_cast(f16x4, ar), bfrag, oacc[dt], 0, 0, 0);
      }
    }

    __syncthreads();   // drains vmcnt (st+1 loads) + orders buf reuse
  }

  // ---- softmax denominator ----
  lsum += __shfl_xor(lsum, 16, 64);
  lsum += __shfl_xor(lsum, 32, 64);
  if (l < 16) lds_red[wid][l] = lsum;
  __syncthreads();
  const float inv = 1.0f / ((lds_red[0][c] + lds_red[1][c]) + (lds_red[2][c] + lds_red[3][c]));

  // ---- cross-wave out reduce (aliases staging LDS, stride 68) ----
  float* ored = (float*)smem;            // [4 waves][16 q][68]
  #pragma unroll
  for (int dt = 0; dt < 4; ++dt) {
    f32x4 o = oacc[dt];
    o[0] *= inv; o[1] *= inv; o[2] *= inv; o[3] *= inv;
    *(f32x4*)&ored[(wid * 16 + c) * 68 + dt * 16 + 4 * g] = o;
  }
  __syncthreads();
  {
    const int q = t >> 4;
    const int d0 = (t & 15) * 4;
    f32x4 s0 = *(const f32x4*)&ored[(0 * 16 + q) * 68 + d0];
    f32x4 s1 = *(const f32x4*)&ored[(1 * 16 + q) * 68 + d0];
    f32x4 s2 = *(const f32x4*)&ored[(2 * 16 + q) * 68 + d0];
    f32x4 s3 = *(const f32x4*)&ored[(3 * 16 + q) * 68 + d0];
    f32x4 s;
    s[0] = (s0[0] + s1[0]) + (s2[0] + s3[0]);
    s[1] = (s0[1] + s1[1]) + (s2[1] + s3[1]);
    s[2] = (s0[2] + s1[2]) + (s2[2] + s3[2]);
    s[3] = (s0[3] + s1[3]) + (s2[3] + s3[3]);
    u32x2 pk;
    pk[0] = pk_f16(s[0], s[1]);
    pk[1] = pk_f16(s[2], s[3]);
    *(u32x2*)&oc[((size_t)(qt * 16 + q) * 2 + b) * 1024 + h * 64 + d0] = pk;
  }

  // ---- attn write (normalized), unpack fp16 p ----
  float* arow = attn + ((size_t)(b * 16 + h) * S_ + qt * 16 + c) * S_ + ct * 16;
  #pragma unroll
  for (int st = 0; st < 32; ++st) {
    f16x2 h0 = __builtin_bit_cast(f16x2, psc0[st]);
    f16x2 h1 = __builtin_bit_cast(f16x2, psc1[st]);
    f32x4 o;
    o[0] = (float)h0[0] * inv;
    o[1] = (float)h0[1] * inv;
    o[2] = (float)h1[0] * inv;
    o[3] = (float)h1[1] * inv;
    *(f32x4*)(arow + (size_t)st * 64 + 4 * g) = o;
  }
  #undef LDSRD
  #undef GLDS
}

// ---------------- out projection (fp16) ----------------
__launch_bounds__(256, 2)
__global__ void k_outproj(const unsigned short* __restrict__ oc, const unsigned short* __restrict__ ow,
                          const float* __restrict__ ob, float* __restrict__ out) {
  __shared__ unsigned short sA[128][40], sB[128][40];
  const int t = threadIdx.x;
  const int wid = t >> 6, l = t & 63, g = l >> 4, c = l & 15;
  const int wr = wid >> 1, wc = wid & 1;
  const int mb = blockIdx.x * 128, nb = blockIdx.y * 128;
  const int sr = t >> 1, sc = (t & 1) * 16;

  f32x4 acc[4][4] = {};
  for (int k0 = 0; k0 < 1024; k0 += 32) {
    __syncthreads();
    {
      const unsigned short* pa = oc + (size_t)(mb + sr) * 1024 + k0 + sc;
      const unsigned short* pb = ow + (size_t)(nb + sr) * 1024 + k0 + sc;
      *(f16x8*)&sA[sr][sc]     = *(const f16x8*)pa;
      *(f16x8*)&sA[sr][sc + 8] = *(const f16x8*)(pa + 8);
      *(f16x8*)&sB[sr][sc]     = *(const f16x8*)pb;
      *(f16x8*)&sB[sr][sc + 8] = *(const f16x8*)(pb + 8);
    }
    __syncthreads();
    f16x8 af[4], bf[4];
    #pragma unroll
    for (int i = 0; i < 4; ++i) {
      af[i] = *(const f16x8*)&sA[wr * 64 + i * 16 + c][g * 8];
      bf[i] = *(const f16x8*)&sB[wc * 64 + i * 16 + c][g * 8];
    }
    #pragma unroll
    for (int i = 0; i < 4; ++i)
      #pragma unroll
      for (int j = 0; j < 4; ++j)
        acc[i][j] = __builtin_amdgcn_mfma_f32_16x16x32_f16(af[i], bf[j], acc[i][j], 0, 0, 0);
  }
  #pragma unroll
  for (int i = 0; i < 4; ++i)
    #pragma unroll
    for (int j = 0; j < 4; ++j)
      #pragma unroll
      for (int rr = 0; rr < 4; ++rr) {
        int m = mb + wr * 64 + i * 16 + 4 * g + rr;
        int n = nb + wc * 64 + j * 16 + c;
        out[(size_t)m * 1024 + n] = acc[i][j][rr] + ob[n];
      }
}

extern "C" void kernel_launch(void* const* d_in, const int* in_sizes, int n_in,
                              void* d_out, int out_size, void* d_ws, size_t ws_size,
                              hipStream_t stream) {
  (void)in_sizes; (void)n_in; (void)out_size; (void)ws_size;
  const float* query = (const float*)d_in[0];
  const float* keyi  = (const float*)d_in[1];
  const float* value = (const float*)d_in[2];
  const float* posb  = (const float*)d_in[3];
  const float* ipw   = (const float*)d_in[4];
  const float* ipb   = (const float*)d_in[5];
  const float* outw  = (const float*)d_in[6];
  const float* outb  = (const float*)d_in[7];
  float* out = (float*)d_out;
  float* attn = out + (size_t)S_ * B_ * E_;

  char* ws = (char*)d_ws;
  size_t off = 0;
  auto alloc = [&](size_t bytes) -> void* {
    void* p = ws + off;
    off += (bytes + 255) & ~(size_t)255;
    return p;
  };
  const size_t NTOK = (size_t)S_ * B_;  // 4096
  unsigned short* qx   = (unsigned short*)alloc(NTOK * 1024 * 2);
  unsigned short* kx   = (unsigned short*)alloc(NTOK * 1024 * 2);
  unsigned short* vx   = (unsigned short*)alloc(NTOK * 1024 * 2);
  unsigned short* w3   = (unsigned short*)alloc((size_t)3072 * 1024 * 2);
  unsigned short* ow   = (unsigned short*)alloc((size_t)1024 * 1024 * 2);
  unsigned short* pb16 = (unsigned short*)alloc((size_t)B_ * S_ * S_ * 2);
  unsigned short* qf   = (unsigned short*)alloc(NTOK * 1024 * 2);
  unsigned short* kf   = (unsigned short*)alloc(NTOK * 1024 * 2);
  unsigned short* VT   = (unsigned short*)alloc((size_t)2 * 1024 * 2048 * 2);
  unsigned short* oc   = (unsigned short*)alloc(NTOK * 1024 * 2);

  k_cvt_all<<<3072, 256, 0, stream>>>(query, keyi, value, ipw, outw, posb,
                                      qx, kx, vx, w3, ow, pb16);

  k_proj_qk<<<dim3(32, 8, 2), 256, 0, stream>>>(qx, kx, w3, ipb, qf, kf);
  k_proj_v<<<dim3(8, 32), 256, 0, stream>>>(w3 + (size_t)2048 * 1024, vx, ipb, VT);
  k_attn_pv<<<4096, 256, 0, stream>>>(qf, kf, VT, pb16, attn, oc);
  k_outproj<<<dim3(32, 8), 256, 0, stream>>>(oc, ow, outb, out);
}

// Round 22
// 337.143 us; speedup vs baseline: 1.3434x; 1.0546x over previous
//
#include <hip/hip_runtime.h>

#define S_ 2048
#define B_ 2
#define E_ 1024
#define H_ 16

typedef _Float16 f16x8 __attribute__((ext_vector_type(8)));
typedef _Float16 f16x4 __attribute__((ext_vector_type(4)));
typedef _Float16 f16x2 __attribute__((ext_vector_type(2)));
typedef float f32x4 __attribute__((ext_vector_type(4)));
typedef unsigned short us4_t __attribute__((ext_vector_type(4)));
typedef unsigned u32x4 __attribute__((ext_vector_type(4)));
typedef unsigned u32x2 __attribute__((ext_vector_type(2)));

static __device__ __forceinline__ unsigned short f2h(float x) {
  _Float16 h = (_Float16)x;   // RNE
  return __builtin_bit_cast(unsigned short, h);
}
static __device__ __forceinline__ unsigned pk_f16(float a, float b) {
  auto r = __builtin_amdgcn_cvt_pkrtz(a, b);   // lo=a, hi=b (RTZ - p only)
  return __builtin_bit_cast(unsigned, r);
}

// ---------------- all f32 -> fp16 conversions in ONE launch (RNE) ----------------
// vec4 segments: q 1M | k 1M | v 1M | ipw 768K | outw 256K | posb 2M = 6M total
__global__ void k_cvt_all(const float* __restrict__ q, const float* __restrict__ k,
                          const float* __restrict__ v, const float* __restrict__ ipw,
                          const float* __restrict__ outw, const float* __restrict__ posb,
                          unsigned short* __restrict__ qx, unsigned short* __restrict__ kx,
                          unsigned short* __restrict__ vx, unsigned short* __restrict__ w3,
                          unsigned short* __restrict__ ow, unsigned short* __restrict__ pb16) {
  const int M1 = 1 << 20;
  int i = blockIdx.x * blockDim.x + threadIdx.x;
  int stp = gridDim.x * blockDim.x;
  for (; i < 6 * M1; i += stp) {
    const float* src;
    unsigned short* dst;
    int j;
    if (i < M1)                   { src = q;    dst = qx;   j = i; }
    else if (i < 2 * M1)          { src = k;    dst = kx;   j = i - M1; }
    else if (i < 3 * M1)          { src = v;    dst = vx;   j = i - 2 * M1; }
    else if (i < 3 * M1 + 786432) { src = ipw;  dst = w3;   j = i - 3 * M1; }
    else if (i < 4 * M1)          { src = outw; dst = ow;   j = i - 3 * M1 - 786432; }
    else                          { src = posb; dst = pb16; j = i - 4 * M1; }
    f32x4 x = ((const f32x4*)src)[j];
    us4_t h;
    #pragma unroll
    for (int e = 0; e < 4; ++e) h[e] = f2h(x[e]);
    ((us4_t*)dst)[j] = h;
  }
}

// ---------------- unified projections: q,k (roles 0,1) + v (role 2) ----------------
// Flat grid of 768 blocks. bid<512: qk-role (z=bid>>8, nb=(bid>>5)&7, mb=bid&31):
//   C[m][n] = A[m][:] . W[n][:] (+bias)*scale -> qf/kf, row-major [4096][1024].
// bid>=512: v-role (g=bid-512: mb=g&7 -> e' base, nb=g>>3 -> j base):
//   VT[b][e'][j] = wv[e'][:] . v[j,b][:] + bias -> fp16 V^T layout.
// Identical tile shape (128x128, K=1024), LDS, and MFMA count per block.
__launch_bounds__(256, 2)
__global__ void k_proj_all(const unsigned short* __restrict__ qx, const unsigned short* __restrict__ kx,
                           const unsigned short* __restrict__ vx, const unsigned short* __restrict__ w3,
                           const float* __restrict__ bias,
                           unsigned short* __restrict__ qf, unsigned short* __restrict__ kf,
                           unsigned short* __restrict__ VT) {
  const int bid = blockIdx.x;
  const int t = threadIdx.x;
  const int wid = t >> 6, l = t & 63, g = l >> 4, c = l & 15;
  const int wr = wid >> 1, wc = wid & 1;
  const int sr = t >> 1, sc = (t & 1) * 16;

  __shared__ unsigned short sA[128][40], sB[128][40];

  const unsigned short* pa_base;
  const unsigned short* pb_base;
  int mb, nb;
  if (bid < 512) {
    const int z = bid >> 8;
    mb = (bid & 31) * 128;
    nb = ((bid >> 5) & 7) * 128;
    pa_base = (z ? kx : qx) + (size_t)(mb + sr) * 1024;
    pb_base = w3 + (size_t)z * (1024 * 1024) + (size_t)(nb + sr) * 1024;
  } else {
    const int gg = bid - 512;
    mb = (gg & 7) * 128;           // e' base
    nb = (gg >> 3) * 128;          // n = b*2048 + j
    const int bb = nb >> 11, jb = nb & 2047;
    pa_base = w3 + (size_t)2048 * 1024 + (size_t)(mb + sr) * 1024;
    pb_base = vx + ((size_t)(jb + sr) * 2 + bb) * 1024;
  }

  f32x4 acc[4][4] = {};
  for (int k0 = 0; k0 < 1024; k0 += 32) {
    __syncthreads();
    {
      const unsigned short* pa = pa_base + k0 + sc;
      const unsigned short* pb = pb_base + k0 + sc;
      *(f16x8*)&sA[sr][sc]     = *(const f16x8*)pa;
      *(f16x8*)&sA[sr][sc + 8] = *(const f16x8*)(pa + 8);
      *(f16x8*)&sB[sr][sc]     = *(const f16x8*)pb;
      *(f16x8*)&sB[sr][sc + 8] = *(const f16x8*)(pb + 8);
    }
    __syncthreads();
    f16x8 af[4], bf[4];
    #pragma unroll
    for (int i = 0; i < 4; ++i) {
      af[i] = *(const f16x8*)&sA[wr * 64 + i * 16 + c][g * 8];
      bf[i] = *(const f16x8*)&sB[wc * 64 + i * 16 + c][g * 8];
    }
    #pragma unroll
    for (int i = 0; i < 4; ++i)
      #pragma unroll
      for (int j = 0; j < 4; ++j)
        acc[i][j] = __builtin_amdgcn_mfma_f32_16x16x32_f16(af[i], bf[j], acc[i][j], 0, 0, 0);
  }

  if (bid < 512) {
    const int z = bid >> 8;
    unsigned short* C = z ? kf : qf;
    const float* bia = bias + z * 1024;
    const float scale = z ? 1.0f : 0.125f;
    #pragma unroll
    for (int i = 0; i < 4; ++i)
      #pragma unroll
      for (int j = 0; j < 4; ++j)
        #pragma unroll
        for (int rr = 0; rr < 4; ++rr) {
          int m = mb + wr * 64 + i * 16 + 4 * g + rr;
          int n = nb + wc * 64 + j * 16 + c;
          float v = (acc[i][j][rr] + bia[n]) * scale;
          C[(size_t)m * 1024 + n] = f2h(v);
        }
  } else {
    const int bb = nb >> 11, jb = nb & 2047;
    #pragma unroll
    for (int i = 0; i < 4; ++i)
      #pragma unroll
      for (int j = 0; j < 4; ++j)
        #pragma unroll
        for (int rr = 0; rr < 4; ++rr) {
          int m = mb + wr * 64 + i * 16 + 4 * g + rr;
          int jj = jb + wc * 64 + j * 16 + c;
          float v = acc[i][j][rr] + bias[2048 + m];
          VT[(size_t)bb * (1024 * 2048) + (size_t)m * 2048 + jj] = f2h(v);
        }
  }
}

// ---------------- fused attention v8b (R19-verified best) ----------------
// Block=(b,h,qt), 256 thr = 4 waves; wave ct owns cols ct*16 of each KVBLK=64.
// QK: 2x mfma_f32_16x16x32_f16; acc@(g,c)=s[k=4g+rr][q=c] == B-frag of K=16
// MFMA -> PV B direct from packed fp16 p regs. p = exp(s-8) (cancels in norm).
// Staging: global_load_lds w=16, linear LDS dest (wave base + lane*16B), XOR
// swizzle folded into per-lane GLOBAL source slot (rule #21). Loads for st+1
// issue at stage-st top; stage-end __syncthreads drains them. fp16 posb.
__launch_bounds__(256, 4)
__global__ void k_attn_pv(const unsigned short* __restrict__ qf, const unsigned short* __restrict__ kf,
                          const unsigned short* __restrict__ VT, const unsigned short* __restrict__ pb16,
                          float* __restrict__ attn, unsigned short* __restrict__ oc) {
  // h-major XCD chunking (R6-validated)
  const int swz = (int)((blockIdx.x & 7) * 512 + (blockIdx.x >> 3));
  const int h = swz >> 8;
  const int b = (swz >> 7) & 1;
  const int qt = swz & 127;

  const int t = threadIdx.x;
  const int wid = t >> 6, l = t & 63, g = l >> 4, c = l & 15;
  const int ct = wid;

  __shared__ unsigned smem[8192];        // S_k[2][2048] S_v[2][2048]
  __shared__ float lds_red[4][16];
  unsigned* S_k = smem;
  unsigned* S_v = smem + 4096;

  const size_t qoff = ((size_t)(qt * 16 + c) * 2 + b) * 1024 + h * 64 + g * 8;
  const f16x8 qfr0 = *(const f16x8*)(qf + qoff);
  const f16x8 qfr1 = *(const f16x8*)(qf + qoff + 32);

  const unsigned short* kfb = kf + (size_t)b * 1024 + h * 64;
  const unsigned short* vtb = VT + ((size_t)b * 1024 + h * 64) * 2048;
  const unsigned short* pbRow = pb16 + (size_t)b * S_ * S_ + (size_t)(qt * 16 + c) * S_ + ct * 16;

  const int rb = t >> 3;                 // 0..31
  const int lsl = (t & 7) ^ (rb & 7);    // pre-swizzled global slot

  #define LDSRD(base, row, slot) \
    __builtin_bit_cast(f16x8, *(const u32x4*)&(base)[(row) * 32 + ((((slot) ^ ((row) & 7))) * 4)])

  #define GLDS(stg, buf) do { \
    __builtin_amdgcn_global_load_lds( \
        (const __attribute__((address_space(1))) unsigned*)(kfb + (size_t)((stg) * 64 + rb) * 2048 + lsl * 8), \
        (__attribute__((address_space(3))) unsigned*)&S_k[(buf) * 2048 + wid * 256], 16, 0, 0); \
    __builtin_amdgcn_global_load_lds( \
        (const __attribute__((address_space(1))) unsigned*)(kfb + (size_t)((stg) * 64 + rb + 32) * 2048 + lsl * 8), \
        (__attribute__((address_space(3))) unsigned*)&S_k[(buf) * 2048 + 1024 + wid * 256], 16, 0, 0); \
    __builtin_amdgcn_global_load_lds( \
        (const __attribute__((address_space(1))) unsigned*)(vtb + (size_t)rb * 2048 + (stg) * 64 + lsl * 8), \
        (__attribute__((address_space(3))) unsigned*)&S_v[(buf) * 2048 + wid * 256], 16, 0, 0); \
    __builtin_amdgcn_global_load_lds( \
        (const __attribute__((address_space(1))) unsigned*)(vtb + (size_t)(rb + 32) * 2048 + (stg) * 64 + lsl * 8), \
        (__attribute__((address_space(3))) unsigned*)&S_v[(buf) * 2048 + 1024 + wid * 256], 16, 0, 0); \
  } while (0)

  f32x4 bias[2];
  unsigned psc0[32], psc1[32];
  float lsum = 0.f;
  f32x4 oacc[4] = {};

  // prologue: stage 0 -> buf 0; bias0 (fp16 -> f32, minus 8)
  GLDS(0, 0);
  {
    f16x4 b0 = *(const f16x4*)(pbRow + 4 * g);
    bias[0][0] = (float)b0[0] - 8.f; bias[0][1] = (float)b0[1] - 8.f;
    bias[0][2] = (float)b0[2] - 8.f; bias[0][3] = (float)b0[3] - 8.f;
  }
  __syncthreads();   // drains vmcnt -> buf0 ready

  #pragma unroll
  for (int st = 0; st < 32; ++st) {
    const int cur = st & 1;
    // issue loads for st+1 into buf^1 (read last at st-1; barrier separated)
    if (st < 31) GLDS(st + 1, cur ^ 1);
    if (st < 31) {
      f16x4 bb = *(const f16x4*)(pbRow + (st + 1) * 64 + 4 * g);
      bias[cur ^ 1][0] = (float)bb[0] - 8.f; bias[cur ^ 1][1] = (float)bb[1] - 8.f;
      bias[cur ^ 1][2] = (float)bb[2] - 8.f; bias[cur ^ 1][3] = (float)bb[3] - 8.f;
    }

    // ---- QK(st): 2 MFMAs, independent chains ----
    {
      const int row = ct * 16 + c;
      const unsigned* kb = S_k + cur * 2048;
      f16x8 kfr0 = LDSRD(kb, row, g);
      f16x8 kfr1 = LDSRD(kb, row, 4 + g);
      f32x4 aA = {}, aB = {};
      aA = __builtin_amdgcn_mfma_f32_16x16x32_f16(kfr0, qfr0, aA, 0, 0, 0);
      aB = __builtin_amdgcn_mfma_f32_16x16x32_f16(kfr1, qfr1, aB, 0, 0, 0);
      float p0 = __expf(aA[0] + aB[0] + bias[cur][0]);
      float p1 = __expf(aA[1] + aB[1] + bias[cur][1]);
      float p2 = __expf(aA[2] + aB[2] + bias[cur][2]);
      float p3 = __expf(aA[3] + aB[3] + bias[cur][3]);
      lsum += (p0 + p1) + (p2 + p3);
      psc0[st] = pk_f16(p0, p1);
      psc1[st] = pk_f16(p2, p3);
    }

    // ---- PV(st): B from psc regs (fp16, K=16); A = V^T from LDS ----
    {
      u32x2 br; br[0] = psc0[st]; br[1] = psc1[st];
      const f16x4 bfrag = __builtin_bit_cast(f16x4, br);
      const unsigned* vb = S_v + cur * 2048;
      #pragma unroll
      for (int dt = 0; dt < 4; ++dt) {
        const int row = dt * 16 + c;
        const int sl = (2 * ct + (g >> 1)) ^ (row & 7);
        u32x2 ar = *(const u32x2*)&vb[row * 32 + sl * 4 + 2 * (g & 1)];
        oacc[dt] = __builtin_amdgcn_mfma_f32_16x16x16f16(__builtin_bit_cast(f16x4, ar), bfrag, oacc[dt], 0, 0, 0);
      }
    }

    __syncthreads();   // drains vmcnt (st+1 loads) + orders buf reuse
  }

  // ---- softmax denominator ----
  lsum += __shfl_xor(lsum, 16, 64);
  lsum += __shfl_xor(lsum, 32, 64);
  if (l < 16) lds_red[wid][l] = lsum;
  __syncthreads();
  const float inv = 1.0f / ((lds_red[0][c] + lds_red[1][c]) + (lds_red[2][c] + lds_red[3][c]));

  // ---- cross-wave out reduce (aliases staging LDS, stride 68) ----
  float* ored = (float*)smem;            // [4 waves][16 q][68]
  #pragma unroll
  for (int dt = 0; dt < 4; ++dt) {
    f32x4 o = oacc[dt];
    o[0] *= inv; o[1] *= inv; o[2] *= inv; o[3] *= inv;
    *(f32x4*)&ored[(wid * 16 + c) * 68 + dt * 16 + 4 * g] = o;
  }
  __syncthreads();
  {
    const int q = t >> 4;
    const int d0 = (t & 15) * 4;
    f32x4 s0 = *(const f32x4*)&ored[(0 * 16 + q) * 68 + d0];
    f32x4 s1 = *(const f32x4*)&ored[(1 * 16 + q) * 68 + d0];
    f32x4 s2 = *(const f32x4*)&ored[(2 * 16 + q) * 68 + d0];
    f32x4 s3 = *(const f32x4*)&ored[(3 * 16 + q) * 68 + d0];
    f32x4 s;
    s[0] = (s0[0] + s1[0]) + (s2[0] + s3[0]);
    s[1] = (s0[1] + s1[1]) + (s2[1] + s3[1]);
    s[2] = (s0[2] + s1[2]) + (s2[2] + s3[2]);
    s[3] = (s0[3] + s1[3]) + (s2[3] + s3[3]);
    u32x2 pk;
    pk[0] = pk_f16(s[0], s[1]);
    pk[1] = pk_f16(s[2], s[3]);
    *(u32x2*)&oc[((size_t)(qt * 16 + q) * 2 + b) * 1024 + h * 64 + d0] = pk;
  }

  // ---- attn write (normalized), unpack fp16 p ----
  float* arow = attn + ((size_t)(b * 16 + h) * S_ + qt * 16 + c) * S_ + ct * 16;
  #pragma unroll
  for (int st = 0; st < 32; ++st) {
    f16x2 h0 = __builtin_bit_cast(f16x2, psc0[st]);
    f16x2 h1 = __builtin_bit_cast(f16x2, psc1[st]);
    f32x4 o;
    o[0] = (float)h0[0] * inv;
    o[1] = (float)h0[1] * inv;
    o[2] = (float)h1[0] * inv;
    o[3] = (float)h1[1] * inv;
    *(f32x4*)(arow + (size_t)st * 64 + 4 * g) = o;
  }
  #undef LDSRD
  #undef GLDS
}

// ---------------- out projection (fp16) ----------------
__launch_bounds__(256, 2)
__global__ void k_outproj(const unsigned short* __restrict__ oc, const unsigned short* __restrict__ ow,
                          const float* __restrict__ ob, float* __restrict__ out) {
  __shared__ unsigned short sA[128][40], sB[128][40];
  const int t = threadIdx.x;
  const int wid = t >> 6, l = t & 63, g = l >> 4, c = l & 15;
  const int wr = wid >> 1, wc = wid & 1;
  const int mb = blockIdx.x * 128, nb = blockIdx.y * 128;
  const int sr = t >> 1, sc = (t & 1) * 16;

  f32x4 acc[4][4] = {};
  for (int k0 = 0; k0 < 1024; k0 += 32) {
    __syncthreads();
    {
      const unsigned short* pa = oc + (size_t)(mb + sr) * 1024 + k0 + sc;
      const unsigned short* pb = ow + (size_t)(nb + sr) * 1024 + k0 + sc;
      *(f16x8*)&sA[sr][sc]     = *(const f16x8*)pa;
      *(f16x8*)&sA[sr][sc + 8] = *(const f16x8*)(pa + 8);
      *(f16x8*)&sB[sr][sc]     = *(const f16x8*)pb;
      *(f16x8*)&sB[sr][sc + 8] = *(const f16x8*)(pb + 8);
    }
    __syncthreads();
    f16x8 af[4], bf[4];
    #pragma unroll
    for (int i = 0; i < 4; ++i) {
      af[i] = *(const f16x8*)&sA[wr * 64 + i * 16 + c][g * 8];
      bf[i] = *(const f16x8*)&sB[wc * 64 + i * 16 + c][g * 8];
    }
    #pragma unroll
    for (int i = 0; i < 4; ++i)
      #pragma unroll
      for (int j = 0; j < 4; ++j)
        acc[i][j] = __builtin_amdgcn_mfma_f32_16x16x32_f16(af[i], bf[j], acc[i][j], 0, 0, 0);
  }
  #pragma unroll
  for (int i = 0; i < 4; ++i)
    #pragma unroll
    for (int j = 0; j < 4; ++j)
      #pragma unroll
      for (int rr = 0; rr < 4; ++rr) {
        int m = mb + wr * 64 + i * 16 + 4 * g + rr;
        int n = nb + wc * 64 + j * 16 + c;
        out[(size_t)m * 1024 + n] = acc[i][j][rr] + ob[n];
      }
}

extern "C" void kernel_launch(void* const* d_in, const int* in_sizes, int n_in,
                              void* d_out, int out_size, void* d_ws, size_t ws_size,
                              hipStream_t stream) {
  (void)in_sizes; (void)n_in; (void)out_size; (void)ws_size;
  const float* query = (const float*)d_in[0];
  const float* keyi  = (const float*)d_in[1];
  const float* value = (const float*)d_in[2];
  const float* posb  = (const float*)d_in[3];
  const float* ipw   = (const float*)d_in[4];
  const float* ipb   = (const float*)d_in[5];
  const float* outw  = (const float*)d_in[6];
  const float* outb  = (const float*)d_in[7];
  float* out = (float*)d_out;
  float* attn = out + (size_t)S_ * B_ * E_;

  char* ws = (char*)d_ws;
  size_t off = 0;
  auto alloc = [&](size_t bytes) -> void* {
    void* p = ws + off;
    off += (bytes + 255) & ~(size_t)255;
    return p;
  };
  const size_t NTOK = (size_t)S_ * B_;  // 4096
  unsigned short* qx   = (unsigned short*)alloc(NTOK * 1024 * 2);
  unsigned short* kx   = (unsigned short*)alloc(NTOK * 1024 * 2);
  unsigned short* vx   = (unsigned short*)alloc(NTOK * 1024 * 2);
  unsigned short* w3   = (unsigned short*)alloc((size_t)3072 * 1024 * 2);
  unsigned short* ow   = (unsigned short*)alloc((size_t)1024 * 1024 * 2);
  unsigned short* pb16 = (unsigned short*)alloc((size_t)B_ * S_ * S_ * 2);
  unsigned short* qf   = (unsigned short*)alloc(NTOK * 1024 * 2);
  unsigned short* kf   = (unsigned short*)alloc(NTOK * 1024 * 2);
  unsigned short* VT   = (unsigned short*)alloc((size_t)2 * 1024 * 2048 * 2);
  unsigned short* oc   = (unsigned short*)alloc(NTOK * 1024 * 2);

  k_cvt_all<<<3072, 256, 0, stream>>>(query, keyi, value, ipw, outw, posb,
                                      qx, kx, vx, w3, ow, pb16);

  k_proj_all<<<768, 256, 0, stream>>>(qx, kx, vx, w3, ipb, qf, kf, VT);
  k_attn_pv<<<4096, 256, 0, stream>>>(qf, kf, VT, pb16, attn, oc);
  k_outproj<<<dim3(32, 8), 256, 0, stream>>>(oc, ow, outb, out);
}